// Round 8
// baseline (378.211 us; speedup 1.0000x reference)
//
#include <hip/hip_runtime.h>
#include <hip/hip_bf16.h>

#define N_NODES_C 20000
#define N_EDGES_C 200000

#define PW0_C       0.17677669529663687f   // sqrt(1/32)
#define PW1_C       0.30618621784789724f   // sqrt(3/32)
#define INV_SQRT3_C 0.57735026918962576f
#define SI_NORM_C   0.25f                  // 1/sqrt(16)

typedef __attribute__((ext_vector_type(8))) short short8;
typedef __attribute__((ext_vector_type(4))) float f32x4;

__device__ __forceinline__ unsigned short f2bf(float x) {
    union { float f; unsigned u; } v; v.f = x;
    unsigned r = v.u + 0x7fffu + ((v.u >> 16) & 1u);   // RNE
    return (unsigned short)(r >> 16);
}
__device__ __forceinline__ float bf2f(unsigned short v) {
    union { unsigned u; float f; } x; x.u = ((unsigned)v) << 16; return x.f;
}

// ---------------- K0b: repack w2 -> bf16 B-fragment layout ----------------
// dest[tid]: tid = ((u*4+k)*2+ks)*512 + l*8 + j
// value = w2[ ks*32 + (l>>4)*8 + j ][ k*256 + u*16 + (l&15) ]
__global__ __launch_bounds__(256) void k_w2(const float* __restrict__ w2,
                                            unsigned short* __restrict__ w2f) {
    int tid = blockIdx.x * 256 + threadIdx.x;        // 65536 exact
    int j  = tid & 7;
    int l  = (tid >> 3) & 63;
    int ks = (tid >> 9) & 1;
    int tp = tid >> 10;                              // u*4+k
    int u = tp >> 2, k = tp & 3;
    int krow = ks * 32 + (l >> 4) * 8 + j;
    int col  = k * 256 + u * 16 + (l & 15);
    w2f[tid] = f2bf(w2[krow * 1024 + col]);
}

// ---------------- K_si: self-interaction, writes (initializes) d_out ------
__global__ __launch_bounds__(256) void k_si(const float* __restrict__ nf,
                                            const float* __restrict__ wsi0,
                                            const float* __restrict__ wsi1,
                                            float* __restrict__ out) {
    int idx = blockIdx.x * 256 + threadIdx.x;        // 20000*64 = 1.28M exact
    int n = idx >> 6, c = idx & 63;
    const float* x = nf + (size_t)n * 64;
    float acc = 0.f;
    if (c < 16) {
        #pragma unroll
        for (int u = 0; u < 16; ++u) acc = fmaf(x[u], wsi0[u * 16 + c], acc);
    } else {
        int w = (c - 16) / 3, m = (c - 16) - w * 3;
        #pragma unroll
        for (int u = 0; u < 16; ++u) acc = fmaf(x[16 + u * 3 + m], wsi1[u * 16 + w], acc);
    }
    out[idx] = acc * SI_NORM_C;
}

// ---------------- CSR build ----------------
__global__ __launch_bounds__(256) void k_count(const int* __restrict__ ei,
                                               int* __restrict__ cnt) {
    int e = blockIdx.x * 256 + threadIdx.x;
    if (e < N_EDGES_C) atomicAdd(&cnt[ei[e]], 1);
}

__global__ __launch_bounds__(1024) void k_scan(const int* __restrict__ cnt,
                                               int* __restrict__ base) {
    __shared__ int wsum[16];
    __shared__ int carry_s;
    if (threadIdx.x == 0) carry_s = 0;
    int lane = threadIdx.x & 63, wid = threadIdx.x >> 6;
    __syncthreads();
    for (int start = 0; start < N_NODES_C; start += 1024) {
        int i = start + threadIdx.x;
        int v = (i < N_NODES_C) ? cnt[i] : 0;
        int x = v;
        #pragma unroll
        for (int d = 1; d < 64; d <<= 1) {
            int y = __shfl_up(x, d);
            if (lane >= d) x += y;
        }
        if (lane == 63) wsum[wid] = x;
        __syncthreads();
        int woff = 0;
        #pragma unroll
        for (int w = 0; w < 16; ++w) if (w < wid) woff += wsum[w];
        int carry = carry_s;
        if (i < N_NODES_C) base[i] = carry + woff + x - v;   // exclusive
        __syncthreads();
        if (threadIdx.x == 1023) carry_s = carry + woff + x;
    }
    if (threadIdx.x == 0) base[N_NODES_C] = N_EDGES_C;
}

__global__ __launch_bounds__(256) void k_fill(const int* __restrict__ ei,
                                              const int* __restrict__ base,
                                              int* __restrict__ cur,
                                              int* __restrict__ eix) {
    int e = blockIdx.x * 256 + threadIdx.x;
    if (e < N_EDGES_C) {
        int r = ei[e];
        int p = atomicAdd(&cur[r], 1);
        eix[base[r] + p] = e;
    }
}

// ---------------- K_main v6: B pinned in AGPRs + builtin MFMA -------------
// 8 waves = (kcls, uhalf), 64 CSR slots/block. h-MLP fused. Partials via
// LDS atomicAdd. Epilogue: run-length CSR aggregation -> atomicAdd(out).
// AGPR pinning: asm-defined value can't be remat'd from memory (R5/R6 bug);
// builtin MFMA reads B from AGPR directly (AV operand class) with correct
// hazard handling (R7 bug: opaque asm MFMA skipped mandatory wait-states).
#define HS_PAD 72
__global__ __launch_bounds__(512) void
k_main(const float* __restrict__ nf,
       const float* __restrict__ ea,
       const float* __restrict__ sh,
       const int* __restrict__ ei,
       const int* __restrict__ eix,
       const float* __restrict__ w1,
       const float* __restrict__ b1,
       const unsigned short* __restrict__ w2f,
       const float* __restrict__ b2,
       float* __restrict__ out) {
    // R1: phase A = nf_s[64][64] f32 (16K) + ea_s[64][8] f32 (2K)
    //     compute  = P[6][64][17] f32 partials (26112 B)
    __shared__ __align__(16) char R1[26112];
    __shared__ __align__(16) unsigned short S_bf[6][16][64];   // 12 KB
    __shared__ __align__(16) unsigned short hs[64][HS_PAD];    // 9 KB
    __shared__ float sh_s[64][4];                              // 1 KB
    __shared__ int   row_s[64];                                // 256 B

    float (*nf_s)[64]  = (float (*)[64])R1;
    float (*ea_s)[8]   = (float (*)[8])(R1 + 16384);
    float (*P)[64][17] = (float (*)[64][17])R1;

    const int t    = threadIdx.x;          // 0..511
    const int lane = t & 63;
    const int wid  = t >> 6;               // 0..7
    const int kcls = wid & 3;
    const int half = wid >> 2;
    const int e0   = blockIdx.x * 64;
    const int el   = t >> 3;               // 0..63
    const int part = t & 7;                // 0..7
    const int wcol = lane & 15;

    // ---- phase A: gathers ----
    {
        int ep  = eix[e0 + el];
        int col = ei[N_EDGES_C + ep];
        const f32x4* src = (const f32x4*)(nf + (size_t)col * 64);
        *(f32x4*)&nf_s[el][part * 8]     = src[part * 2];
        *(f32x4*)&nf_s[el][part * 8 + 4] = src[part * 2 + 1];
        ea_s[el][part] = ea[(size_t)ep * 8 + part];
        if (part == 0) {
            *(f32x4*)&sh_s[el][0] = *(const f32x4*)(sh + (size_t)ep * 4);
            row_s[el] = ei[ep];
        }
    }
    // B-fragments for this wave's (kcls, half) -> AGPRs (64 AGPR), b2 -> 8 VGPR
    short8 B0[8], B1[8];
    float  bb[8];
    #pragma unroll
    for (int uu = 0; uu < 8; ++uu) {
        int u = half * 8 + uu;
        const unsigned short* wk = w2f + (u * 4 + kcls) * 1024 + lane * 8;
        short8 t0 = *(const short8*)(wk);
        short8 t1 = *(const short8*)(wk + 512);
        asm volatile("" : "=a"(B0[uu]) : "0"(t0));   // pin into AGPR; asm-defined
        asm volatile("" : "=a"(B1[uu]) : "0"(t1));   // value cannot be remat'd
        bb[uu] = b2[kcls * 256 + u * 16 + wcol];
    }
    __syncthreads();

    // ---- phase B: S scalars (bf16) + h-MLP into LDS ----
    {
        float y0 = sh_s[el][0], y1x = sh_s[el][1], y1y = sh_s[el][2], y1z = sh_s[el][3];
        #pragma unroll
        for (int uu = 0; uu < 2; ++uu) {
            int u = part * 2 + uu;
            float xs = nf_s[el][u];
            float v0 = nf_s[el][16 + u * 3 + 0];
            float v1 = nf_s[el][16 + u * 3 + 1];
            float v2 = nf_s[el][16 + u * 3 + 2];
            float dot = v0 * y1x + v1 * y1y + v2 * y1z;
            S_bf[0][u][el] = f2bf(xs * y0);
            S_bf[1][u][el] = f2bf(xs);
            S_bf[2][u][el] = f2bf(v0);
            S_bf[3][u][el] = f2bf(v1);
            S_bf[4][u][el] = f2bf(v2);
            S_bf[5][u][el] = f2bf(INV_SQRT3_C * dot);
        }
        float a0 = ea_s[el][0], a1 = ea_s[el][1], a2 = ea_s[el][2], a3 = ea_s[el][3];
        float a4 = ea_s[el][4], a5 = ea_s[el][5], a6 = ea_s[el][6], a7 = ea_s[el][7];
        short8 hv;
        #pragma unroll
        for (int j = 0; j < 8; ++j) {
            int c = part * 8 + j;
            float acc = b1[c];
            acc = fmaf(a0, w1[0 * 64 + c], acc);
            acc = fmaf(a1, w1[1 * 64 + c], acc);
            acc = fmaf(a2, w1[2 * 64 + c], acc);
            acc = fmaf(a3, w1[3 * 64 + c], acc);
            acc = fmaf(a4, w1[4 * 64 + c], acc);
            acc = fmaf(a5, w1[5 * 64 + c], acc);
            acc = fmaf(a6, w1[6 * 64 + c], acc);
            acc = fmaf(a7, w1[7 * 64 + c], acc);
            float s = acc / (1.0f + __expf(-acc));
            hv[j] = (short)f2bf(s);
        }
        *(short8*)&hs[el][part * 8] = hv;
    }
    __syncthreads();

    // ---- zero partials (aliases nf_s region; nf_s now dead) ----
    {
        float* Pf = (float*)R1;
        #pragma unroll
        for (int i = 0; i < 13; ++i) {
            int idx = t + i * 512;
            if (idx < 6 * 64 * 17) Pf[idx] = 0.f;
        }
    }
    __syncthreads();

    // ---- compute: wave (kcls, half); 4 tiles of 16 edges ----
    const int g4 = (lane >> 4) << 2;

    #pragma unroll 1
    for (int tt = 0; tt < 4; ++tt) {
        int row = tt * 16 + (lane & 15);
        short8 a0 = *(const short8*)&hs[row][(lane >> 4) * 8];
        short8 a1 = *(const short8*)&hs[row][(lane >> 4) * 8 + 32];
        int eb = tt * 16 + g4;
        if (kcls != 2) {
            const int cls = (kcls == 0) ? 0 : (kcls == 1) ? 1 : 5;
            f32x4 acc = {0.f, 0.f, 0.f, 0.f};
            #pragma unroll
            for (int uu = 0; uu < 8; ++uu) {
                int u = half * 8 + uu;
                f32x4 c = {0.f, 0.f, 0.f, 0.f};
                c = __builtin_amdgcn_mfma_f32_16x16x32_bf16(a0, B0[uu], c, 0, 0, 0);
                c = __builtin_amdgcn_mfma_f32_16x16x32_bf16(a1, B1[uu], c, 0, 0, 0);
                unsigned long long sv = *(const unsigned long long*)&S_bf[cls][u][eb];
                #pragma unroll
                for (int r = 0; r < 4; ++r)
                    acc[r] = fmaf(c[r] + bb[uu], bf2f((unsigned short)(sv >> (16 * r))), acc[r]);
            }
            #pragma unroll
            for (int r = 0; r < 4; ++r)
                atomicAdd(&P[cls][eb + r][wcol], acc[r]);
        } else {
            f32x4 qa = {0.f,0.f,0.f,0.f}, qb = {0.f,0.f,0.f,0.f}, qc = {0.f,0.f,0.f,0.f};
            #pragma unroll
            for (int uu = 0; uu < 8; ++uu) {
                int u = half * 8 + uu;
                f32x4 c = {0.f, 0.f, 0.f, 0.f};
                c = __builtin_amdgcn_mfma_f32_16x16x32_bf16(a0, B0[uu], c, 0, 0, 0);
                c = __builtin_amdgcn_mfma_f32_16x16x32_bf16(a1, B1[uu], c, 0, 0, 0);
                unsigned long long s0 = *(const unsigned long long*)&S_bf[2][u][eb];
                unsigned long long s1 = *(const unsigned long long*)&S_bf[3][u][eb];
                unsigned long long s2 = *(const unsigned long long*)&S_bf[4][u][eb];
                #pragma unroll
                for (int r = 0; r < 4; ++r) {
                    float wp = c[r] + bb[uu];
                    qa[r] = fmaf(wp, bf2f((unsigned short)(s0 >> (16 * r))), qa[r]);
                    qb[r] = fmaf(wp, bf2f((unsigned short)(s1 >> (16 * r))), qb[r]);
                    qc[r] = fmaf(wp, bf2f((unsigned short)(s2 >> (16 * r))), qc[r]);
                }
            }
            #pragma unroll
            for (int r = 0; r < 4; ++r) {
                atomicAdd(&P[2][eb + r][wcol], qa[r]);
                atomicAdd(&P[3][eb + r][wcol], qb[r]);
                atomicAdd(&P[4][eb + r][wcol], qc[r]);
            }
        }
    }
    __syncthreads();

    // ---- assembly + run-length CSR aggregation -> atomicAdd(out) ----
    {
        int c  = t & 63;
        int eg = t >> 6;                    // 8 consecutive CSR slots per thread
        int cnode = row_s[eg * 8];
        float run = 0.f;
        if (c < 16) {
            #pragma unroll
            for (int i = 0; i < 8; ++i) {
                int e = eg * 8 + i;
                int nd = row_s[e];
                float val = PW0_C * (P[0][e][c] + P[5][e][c]);
                if (nd != cnode) {          // wave-uniform (one eg per wave)
                    atomicAdd(&out[(size_t)cnode * 64 + c], run);
                    run = 0.f; cnode = nd;
                }
                run += val;
            }
        } else {
            const float c1 = PW1_C * INV_SQRT3_C;
            int w = (c - 16) / 3, m = (c - 16) - 3 * w;
            #pragma unroll
            for (int i = 0; i < 8; ++i) {
                int e = eg * 8 + i;
                int nd = row_s[e];
                float val = c1 * (P[1][e][w] * sh_s[e][1 + m] + P[2 + m][e][w] * sh_s[e][0]);
                if (nd != cnode) {
                    atomicAdd(&out[(size_t)cnode * 64 + c], run);
                    run = 0.f; cnode = nd;
                }
                run += val;
            }
        }
        atomicAdd(&out[(size_t)cnode * 64 + c], run);
    }
}

extern "C" void kernel_launch(void* const* d_in, const int* in_sizes, int n_in,
                              void* d_out, int out_size, void* d_ws, size_t ws_size,
                              hipStream_t stream) {
    const float* nf   = (const float*)d_in[0];
    const float* ea   = (const float*)d_in[1];
    const float* sh   = (const float*)d_in[2];
    const float* w1   = (const float*)d_in[3];
    const float* b1   = (const float*)d_in[4];
    const float* w2   = (const float*)d_in[5];
    const float* b2   = (const float*)d_in[6];
    const float* wsi0 = (const float*)d_in[7];
    const float* wsi1 = (const float*)d_in[8];
    const int*   ei   = (const int*)d_in[9];
    float* out = (float*)d_out;

    // workspace layout
    char* ws = (char*)d_ws;
    unsigned short* w2f  = (unsigned short*)ws;                    // 128 KB
    int* cnt             = (int*)(ws + 131072);
    int* cur             = cnt + N_NODES_C;
    int* base            = cur + N_NODES_C;
    int* eix             = base + N_NODES_C + 1;

    hipMemsetAsync(cnt, 0, 2 * N_NODES_C * sizeof(int), stream);   // cnt + cur

    k_w2   <<<256,   256, 0, stream>>>(w2, w2f);
    k_si   <<<5000,  256, 0, stream>>>(nf, wsi0, wsi1, out);
    k_count<<<(N_EDGES_C + 255) / 256, 256, 0, stream>>>(ei, cnt);
    k_scan <<<1,    1024, 0, stream>>>(cnt, base);
    k_fill <<<(N_EDGES_C + 255) / 256, 256, 0, stream>>>(ei, base, cur, eix);
    k_main <<<3125,  512, 0, stream>>>(nf, ea, sh, ei, eix, w1, b1, w2f, b2, out);
}

// Round 9
// 203.713 us; speedup vs baseline: 1.8566x; 1.8566x over previous
//
#include <hip/hip_runtime.h>
#include <hip/hip_bf16.h>

#define N_NODES_C 20000
#define N_EDGES_C 200000

#define PW0_C       0.17677669529663687f   // sqrt(1/32)
#define PW1_C       0.30618621784789724f   // sqrt(3/32)
#define INV_SQRT3_C 0.57735026918962576f
#define SI_NORM_C   0.25f                  // 1/sqrt(16)

typedef __attribute__((ext_vector_type(8))) short short8;
typedef __attribute__((ext_vector_type(4))) float f32x4;

__device__ __forceinline__ unsigned short f2bf(float x) {
    union { float f; unsigned u; } v; v.f = x;
    unsigned r = v.u + 0x7fffu + ((v.u >> 16) & 1u);   // RNE
    return (unsigned short)(r >> 16);
}
__device__ __forceinline__ float bf2f(unsigned short v) {
    union { unsigned u; float f; } x; x.u = ((unsigned)v) << 16; return x.f;
}

// ---------------- K0: h = silu(edge_attr @ w1 + b1), bf16 ----------------
__global__ __launch_bounds__(256) void k_h(const float* __restrict__ ea,
                                           const float* __restrict__ w1,
                                           const float* __restrict__ b1,
                                           unsigned short* __restrict__ h) {
    int idx = blockIdx.x * 256 + threadIdx.x;        // E*64 = 12.8M exact
    int e = idx >> 6, c = idx & 63;
    const float* a = ea + (size_t)e * 8;
    float acc = b1[c];
    #pragma unroll
    for (int k = 0; k < 8; ++k) acc = fmaf(a[k], w1[k * 64 + c], acc);
    float s = acc / (1.0f + __expf(-acc));
    h[idx] = f2bf(s);
}

// ---------------- K0b: repack w2 -> bf16, per-kcls contiguous -------------
// dst = kcls*16384 + u*1024 + ks*512 + l*8 + j
// val = w2[ ks*32 + (l>>4)*8 + j ][ kcls*256 + u*16 + (l&15) ]
__global__ __launch_bounds__(256) void k_w2(const float* __restrict__ w2,
                                            unsigned short* __restrict__ w2f) {
    int tid = blockIdx.x * 256 + threadIdx.x;        // 65536 exact
    int j    = tid & 7;
    int l    = (tid >> 3) & 63;
    int ks   = (tid >> 9) & 1;
    int u    = (tid >> 10) & 15;
    int kcls = tid >> 14;
    int krow = ks * 32 + (l >> 4) * 8 + j;
    int col  = kcls * 256 + u * 16 + (l & 15);
    w2f[tid] = f2bf(w2[krow * 1024 + col]);
}

// ---------------- CSR build ----------------
__global__ __launch_bounds__(256) void k_count(const int* __restrict__ ei,
                                               int* __restrict__ cnt) {
    int e = blockIdx.x * 256 + threadIdx.x;
    if (e < N_EDGES_C) atomicAdd(&cnt[ei[e]], 1);
}

__global__ __launch_bounds__(1024) void k_scan(const int* __restrict__ cnt,
                                               int* __restrict__ base) {
    __shared__ int wsum[16];
    __shared__ int carry_s;
    if (threadIdx.x == 0) carry_s = 0;
    int lane = threadIdx.x & 63, wid = threadIdx.x >> 6;
    __syncthreads();
    for (int start = 0; start < N_NODES_C; start += 1024) {
        int i = start + threadIdx.x;
        int v = (i < N_NODES_C) ? cnt[i] : 0;
        int x = v;
        #pragma unroll
        for (int d = 1; d < 64; d <<= 1) {
            int y = __shfl_up(x, d);
            if (lane >= d) x += y;
        }
        if (lane == 63) wsum[wid] = x;
        __syncthreads();
        int woff = 0;
        #pragma unroll
        for (int w = 0; w < 16; ++w) if (w < wid) woff += wsum[w];
        int carry = carry_s;
        if (i < N_NODES_C) base[i] = carry + woff + x - v;   // exclusive
        __syncthreads();
        if (threadIdx.x == 1023) carry_s = carry + woff + x;
    }
    if (threadIdx.x == 0) base[N_NODES_C] = N_EDGES_C;
}

// pos[e] = CSR slot of edge e
__global__ __launch_bounds__(256) void k_fill(const int* __restrict__ ei,
                                              const int* __restrict__ base,
                                              int* __restrict__ cur,
                                              int* __restrict__ pos) {
    int e = blockIdx.x * 256 + threadIdx.x;
    if (e < N_EDGES_C) {
        int r = ei[e];
        int p = atomicAdd(&cur[r], 1);
        pos[e] = base[r] + p;
    }
}

// ---------------- K_mainS: block = (64-edge tile, kcls); B in LDS once ----
// 256 thr = 4 waves; wave = 16-edge tile. One barrier total. No LDS atomics.
// Output: per-kcls bf16 partials (A0/A1/A2/A3) at sequential edge positions.
__global__ __launch_bounds__(256) void
k_mainS(const float* __restrict__ nf,
        const float* __restrict__ sh,
        const int* __restrict__ ei,
        const unsigned short* __restrict__ h,
        const unsigned short* __restrict__ w2f,
        const float* __restrict__ b2,
        unsigned short* __restrict__ aux) {
    __shared__ __align__(16) unsigned short Bs[16384];      // 32 KB
    __shared__ __align__(16) unsigned short S_bf[3][16][64];// 6 KB
    __shared__ float b2_s[256];                             // 1 KB

    const int t    = threadIdx.x;
    const int lane = t & 63;
    const int w    = t >> 6;                 // wave id 0..3
    const int bid  = blockIdx.x;
    const int kcls = bid & 3;
    const int e0   = (bid >> 2) * 64;

    // ---- stage B chunk (32 KB) into LDS, plain copy ----
    {
        const short8* wsrc = (const short8*)(w2f + kcls * 16384);
        short8* bdst = (short8*)Bs;
        #pragma unroll
        for (int i = 0; i < 8; ++i) bdst[i * 256 + t] = wsrc[i * 256 + t];
        b2_s[t] = b2[kcls * 256 + t];
    }

    // ---- per-edge S scalars for this kcls (thread = (el, part)) ----
    {
        int el = t >> 2, part = t & 3;
        int e  = e0 + el;
        int col = ei[N_EDGES_C + e];
        const float* row = nf + (size_t)col * 64;
        f32x4 shv = *(const f32x4*)(sh + (size_t)e * 4);
        f32x4 xs4 = *(const f32x4*)(row + part * 4);
        f32x4 xa  = *(const f32x4*)(row + 16 + part * 12);
        f32x4 xb  = *(const f32x4*)(row + 16 + part * 12 + 4);
        f32x4 xc  = *(const f32x4*)(row + 16 + part * 12 + 8);
        float xv[12];
        #pragma unroll
        for (int q = 0; q < 4; ++q) { xv[q] = xa[q]; xv[4 + q] = xb[q]; xv[8 + q] = xc[q]; }
        #pragma unroll
        for (int uu = 0; uu < 4; ++uu) {
            int u = part * 4 + uu;
            float xs = xs4[uu];
            float v0 = xv[uu * 3 + 0], v1 = xv[uu * 3 + 1], v2 = xv[uu * 3 + 2];
            if (kcls == 0) {
                S_bf[0][u][el] = f2bf(xs * shv[0]);
            } else if (kcls == 1) {
                S_bf[0][u][el] = f2bf(xs);
            } else if (kcls == 2) {
                S_bf[0][u][el] = f2bf(v0);
                S_bf[1][u][el] = f2bf(v1);
                S_bf[2][u][el] = f2bf(v2);
            } else {
                float dot = v0 * shv[1] + v1 * shv[2] + v2 * shv[3];
                S_bf[0][u][el] = f2bf(INV_SQRT3_C * dot);
            }
        }
    }

    // ---- A fragments (global h, L2-shared across the 4 kcls siblings) ----
    const unsigned short* hrow =
        h + (size_t)(e0 + w * 16 + (lane & 15)) * 64 + ((lane >> 4) * 8);
    short8 a0 = *(const short8*)(hrow);
    short8 a1 = *(const short8*)(hrow + 32);

    __syncthreads();   // single barrier: Bs + S_bf + b2_s ready

    const int wcol = lane & 15;
    const int g4   = (lane >> 4) << 2;
    const int eb   = w * 16 + g4;            // block-local edge row base

    if (kcls != 2) {
        f32x4 acc = {0.f, 0.f, 0.f, 0.f};
        #pragma unroll
        for (int u = 0; u < 16; ++u) {
            short8 b0 = *(const short8*)&Bs[u * 1024 + lane * 8];
            short8 b1 = *(const short8*)&Bs[u * 1024 + 512 + lane * 8];
            f32x4 c = {0.f, 0.f, 0.f, 0.f};
            c = __builtin_amdgcn_mfma_f32_16x16x32_bf16(a0, b0, c, 0, 0, 0);
            c = __builtin_amdgcn_mfma_f32_16x16x32_bf16(a1, b1, c, 0, 0, 0);
            float bb = b2_s[u * 16 + wcol];
            unsigned long long sv = *(const unsigned long long*)&S_bf[0][u][eb];
            #pragma unroll
            for (int r = 0; r < 4; ++r)
                acc[r] = fmaf(c[r] + bb, bf2f((unsigned short)(sv >> (16 * r))), acc[r]);
        }
        // aux region for this kcls: A0 / A1 / A3 each [E][16]
        unsigned short* dst =
            aux + ((kcls == 0) ? (size_t)0 :
                   (kcls == 1) ? (size_t)3200000 : (size_t)16000000);
        #pragma unroll
        for (int r = 0; r < 4; ++r)
            dst[(size_t)(e0 + eb + r) * 16 + wcol] = f2bf(acc[r]);
    } else {
        f32x4 qa = {0.f,0.f,0.f,0.f}, qb = {0.f,0.f,0.f,0.f}, qc = {0.f,0.f,0.f,0.f};
        #pragma unroll
        for (int u = 0; u < 16; ++u) {
            short8 b0 = *(const short8*)&Bs[u * 1024 + lane * 8];
            short8 b1 = *(const short8*)&Bs[u * 1024 + 512 + lane * 8];
            f32x4 c = {0.f, 0.f, 0.f, 0.f};
            c = __builtin_amdgcn_mfma_f32_16x16x32_bf16(a0, b0, c, 0, 0, 0);
            c = __builtin_amdgcn_mfma_f32_16x16x32_bf16(a1, b1, c, 0, 0, 0);
            float bb = b2_s[u * 16 + wcol];
            unsigned long long s0 = *(const unsigned long long*)&S_bf[0][u][eb];
            unsigned long long s1 = *(const unsigned long long*)&S_bf[1][u][eb];
            unsigned long long s2 = *(const unsigned long long*)&S_bf[2][u][eb];
            #pragma unroll
            for (int r = 0; r < 4; ++r) {
                float wp = c[r] + bb;
                qa[r] = fmaf(wp, bf2f((unsigned short)(s0 >> (16 * r))), qa[r]);
                qb[r] = fmaf(wp, bf2f((unsigned short)(s1 >> (16 * r))), qb[r]);
                qc[r] = fmaf(wp, bf2f((unsigned short)(s2 >> (16 * r))), qc[r]);
            }
        }
        unsigned short* dst = aux + (size_t)6400000;        // A2: [E][48], m*16+w
        #pragma unroll
        for (int r = 0; r < 4; ++r) {
            size_t rowb = (size_t)(e0 + eb + r) * 48;
            dst[rowb +      wcol] = f2bf(qa[r]);
            dst[rowb + 16 + wcol] = f2bf(qb[r]);
            dst[rowb + 32 + wcol] = f2bf(qc[r]);
        }
    }
}

// ---------------- K_comb: recombine partials -> bf16 msg at CSR slot ------
__global__ __launch_bounds__(256) void
k_comb(const unsigned short* __restrict__ aux,
       const float* __restrict__ sh,
       const int* __restrict__ pos,
       unsigned short* __restrict__ msgb) {
    int idx = blockIdx.x * 256 + threadIdx.x;        // E*64 exact
    int e = idx >> 6, c = idx & 63;
    const unsigned short* A0 = aux;
    const unsigned short* A1 = aux + 3200000;
    const unsigned short* A2 = aux + 6400000;
    const unsigned short* A3 = aux + 16000000;
    int p = pos[e];
    float val;
    if (c < 16) {
        val = PW0_C * (bf2f(A0[(size_t)e * 16 + c]) + bf2f(A3[(size_t)e * 16 + c]));
    } else {
        int q = c - 16;
        int w = q / 3, m = q - 3 * w;
        f32x4 shv = *(const f32x4*)(sh + (size_t)e * 4);
        float ym = (m == 0) ? shv[1] : (m == 1) ? shv[2] : shv[3];
        val = (PW1_C * INV_SQRT3_C) *
              (bf2f(A1[(size_t)e * 16 + w]) * ym +
               bf2f(A2[(size_t)e * 48 + m * 16 + w]) * shv[0]);
    }
    msgb[(size_t)p * 64 + c] = f2bf(val);
}

// ---------------- K_gather: streaming segmented sum + self-interaction ----
__global__ __launch_bounds__(256) void k_gather(const unsigned short* __restrict__ msgb,
                                                const int* __restrict__ base,
                                                const float* __restrict__ nf,
                                                const float* __restrict__ wsi0,
                                                const float* __restrict__ wsi1,
                                                float* __restrict__ out) {
    int wid = threadIdx.x >> 6, lane = threadIdx.x & 63;
    int n = blockIdx.x * 4 + wid;
    if (n >= N_NODES_C) return;
    int j0 = base[n], j1 = base[n + 1];
    int d = j1 - j0;
    const unsigned short* p = msgb + (size_t)j0 * 64 + lane;
    float acc = 0.f;
    int j = 0;
    for (; j + 8 <= d; j += 8) {    // contiguous 128B rows, 8-way ILP
        float s = 0.f;
        #pragma unroll
        for (int q = 0; q < 8; ++q) s += bf2f(p[(size_t)(j + q) * 64]);
        acc += s;
    }
    for (; j < d; ++j) acc += bf2f(p[(size_t)j * 64]);
    const float* x = nf + (size_t)n * 64;
    float si = 0.f;
    if (lane < 16) {
        #pragma unroll
        for (int u = 0; u < 16; ++u) si = fmaf(x[u], wsi0[u * 16 + lane], si);
    } else {
        int w = (lane - 16) / 3, m = (lane - 16) - w * 3;
        #pragma unroll
        for (int u = 0; u < 16; ++u) si = fmaf(x[16 + u * 3 + m], wsi1[u * 16 + w], si);
    }
    out[(size_t)n * 64 + lane] = acc + si * SI_NORM_C;
}

extern "C" void kernel_launch(void* const* d_in, const int* in_sizes, int n_in,
                              void* d_out, int out_size, void* d_ws, size_t ws_size,
                              hipStream_t stream) {
    const float* nf   = (const float*)d_in[0];
    const float* ea   = (const float*)d_in[1];
    const float* sh   = (const float*)d_in[2];
    const float* w1   = (const float*)d_in[3];
    const float* b1   = (const float*)d_in[4];
    const float* w2   = (const float*)d_in[5];
    const float* b2   = (const float*)d_in[6];
    const float* wsi0 = (const float*)d_in[7];
    const float* wsi1 = (const float*)d_in[8];
    const int*   ei   = (const int*)d_in[9];
    float* out = (float*)d_out;

    // workspace layout (h and msgb alias: h dead before k_comb writes msgb)
    char* ws = (char*)d_ws;
    unsigned short* h    = (unsigned short*)ws;                    // 25.6 MB
    unsigned short* msgb = (unsigned short*)ws;                    // alias of h
    unsigned short* w2f  = (unsigned short*)(ws + 25600000);       // 128 KB
    unsigned short* aux  = (unsigned short*)(ws + 25731072);       // 38.4 MB
    int* cnt             = (int*)(ws + 64131072);                  // 80 KB
    int* cur             = cnt + N_NODES_C;                        // 80 KB
    int* base            = cur + N_NODES_C;                        // 80 KB + 4
    int* pos             = base + N_NODES_C + 1;                   // 800 KB

    hipMemsetAsync(cnt, 0, 2 * N_NODES_C * sizeof(int), stream);   // cnt + cur

    k_h    <<<50000, 256, 0, stream>>>(ea, w1, b1, h);
    k_w2   <<<256,   256, 0, stream>>>(w2, w2f);
    k_count<<<(N_EDGES_C + 255) / 256, 256, 0, stream>>>(ei, cnt);
    k_scan <<<1,    1024, 0, stream>>>(cnt, base);
    k_fill <<<(N_EDGES_C + 255) / 256, 256, 0, stream>>>(ei, base, cur, pos);
    k_mainS<<<12500, 256, 0, stream>>>(nf, sh, ei, h, w2f, b2, aux);
    k_comb <<<50000, 256, 0, stream>>>(aux, sh, pos, msgb);
    k_gather<<<5000, 256, 0, stream>>>(msgb, base, nf, wsi0, wsi1, out);
}